// Round 5
// baseline (283.059 us; speedup 1.0000x reference)
//
#include <hip/hip_runtime.h>

// B=16, C=64, H=W=192, K=3 (fixed).
// Kernel 1: ker[b,c,i,j] from the tiny MLP (16 blocks, writes 9216 floats to ws).
// Kernel 2 (v8): depthwise 3x3, BARRIER-FREE per-wave pipeline.
//   v7 showed the convoy signature (all counters ~1/3 duty): block-wide
//   __syncthreads + vmcnt(0) drains phase-aligned all waves. v8 removes all
//   barriers: grid = 4096 one-wave (64-thread) blocks; each wave owns a
//   48-row band of one plane and a PRIVATE 12 KB circular LDS window
//   (4 slots x 4 rows x 768 B). Rolling jobs of 4 output rows:
//     job w: issue 3x16B global_load_lds for row-group w+2 (slot (w+2)&3),
//            s_waitcnt vmcnt(6)  [in-order retirement: newest 6 = prev
//            job's 3 NT stores + the 3 loads just issued => group w+1 has
//            landed], then compute 4 rows (192 tasks = exactly 3/lane,
//            all wave-uniform -> counted vmcnt is sound), 3 NT stores.
//   No __syncthreads anywhere; waves free-run and self-stagger so HBM,
//   LDS and VALU phases interleave across the ~13 resident waves/CU.
//   All global_load_lds are width 16 (HW-verified); no predicated VMEM.

#define BB 16
#define CC 64
#define HH 192
#define WW 192
#define KERLEN (CC * 9)     // 576 per batch
#define BAND 48             // rows per wave band
#define NJOB 12             // jobs per band (4 rows each)
#define SLOTF 768           // floats per 4-row group slot (4*192)
#define LDSF (4 * SLOTF)    // 3072 floats = 12288 B per wave

typedef float f4 __attribute__((ext_vector_type(4)));

// ---- Kernel 1: generate the 1024 per-(b,c) 3x3 kernels into d_ws ----
__global__ __launch_bounds__(256) void gen_kernels(
    const float* __restrict__ d,   // (B, C)
    const float* __restrict__ w1,  // (C, C)
    const float* __restrict__ w2,  // (C*9, C)
    float* __restrict__ ker)       // (B*C*9)
{
    __shared__ float dd[CC];
    __shared__ float hid[CC];
    const int b = blockIdx.x;
    const int t = threadIdx.x;

    if (t < CC) dd[t] = d[b * CC + t];
    __syncthreads();

    if (t < CC) {
        const float* w1r = w1 + t * CC;
        float acc = 0.f;
        #pragma unroll 8
        for (int m = 0; m < CC; ++m) acc += dd[m] * w1r[m];
        hid[t] = acc > 0.f ? acc : 0.1f * acc;
    }
    __syncthreads();

    for (int o = t; o < KERLEN; o += 256) {
        const float* w2r = w2 + o * CC;
        float acc = 0.f;
        #pragma unroll 8
        for (int k = 0; k < CC; ++k) acc += hid[k] * w2r[k];
        ker[b * KERLEN + o] = acc;
    }
}

#define WAITV(n) do { asm volatile("s_waitcnt vmcnt(" #n ")" ::: "memory"); \
                      __builtin_amdgcn_sched_barrier(0); } while (0)

// ---- Kernel 2: depthwise 3x3, barrier-free per-wave rolling pipeline ----
__global__ __launch_bounds__(64, 3) void dconv3x3_v8(
    const float* __restrict__ x,    // (B*C, H, W)
    const float* __restrict__ ker,  // (B*C, 9)
    float* __restrict__ out)        // (B*C, H, W)
{
    __shared__ __align__(16) float lds[LDSF];   // 12288 B, private to this wave

    const int blk   = blockIdx.x;
    const int bc    = blk >> 2;                 // plane 0..1023
    const int band0 = (blk & 3) * BAND;         // first output row of band

    const int t = threadIdx.x;                  // 0..63

    const float* __restrict__ xp = x   + (size_t)bc * HH * WW;
    float* __restrict__       op = out + (size_t)bc * HH * WW;

    const float* kp = ker + bc * 9;             // block-uniform -> SGPRs
    const float k00 = kp[0], k01 = kp[1], k02 = kp[2];
    const float k10 = kp[3], k11 = kp[4], k12 = kp[5];
    const float k20 = kp[6], k21 = kp[7], k22 = kp[8];

    // --- per-lane staging constants (group = 4 rows = 3072 B = 3 x 1024 B) ---
    int srow_off[3], scol[3];
    #pragma unroll
    for (int c3 = 0; c3 < 3; ++c3) {
        const int b0 = c3 * 1024 + t * 16;      // byte in group
        srow_off[c3] = b0 / 768;                // row in group 0..3
        scol[c3]     = (b0 - srow_off[c3] * 768) >> 2;   // float col
    }

    // stage group g (plane rows band0+4g .. +3, clamped) into slot g&3
    auto stage = [&](int g) {
        #pragma unroll
        for (int c3 = 0; c3 < 3; ++c3) {
            int srow = band0 + 4 * g + srow_off[c3];
            srow = srow < 0 ? 0 : (srow > HH - 1 ? HH - 1 : srow);
            __builtin_amdgcn_global_load_lds(
                (const __attribute__((address_space(1))) unsigned int*)
                    (xp + srow * WW + scol[c3]),
                (__attribute__((address_space(3))) unsigned int*)
                    (lds + (g & 3) * SLOTF + c3 * 256 + t * 4),
                16, 0, 0);
        }
    };

    // --- per-lane compute constants: 3 tasks/lane over (row-in-job, quad) ---
    int rl_i[3], qf_i[3], offL_i[3], offR_i[3];
    bool hasL_i[3], hasR_i[3];
    #pragma unroll
    for (int i = 0; i < 3; ++i) {
        const int task = i * 64 + t;            // 0..191
        const int rl   = task / 48;             // row in job 0..3
        const int q    = task - rl * 48;        // quad col 0..47
        rl_i[i] = rl;
        qf_i[i] = q * 4;                        // float col
        hasL_i[i] = (q > 0);
        hasR_i[i] = (q < 47);
        offL_i[i] = hasL_i[i] ? -1 : 0;
        offR_i[i] = hasR_i[i] ?  4 : 0;
    }

    const f4 zero = {0.f, 0.f, 0.f, 0.f};

    // prologue: groups -1, 0, 1 (9 loads in flight)
    stage(-1); stage(0); stage(1);

    #pragma unroll
    for (int w = 0; w < NJOB; ++w) {
        if (w <= 10) stage(w + 2);              // 3 more loads
        // in-order vmcnt: newest-6 = prev stores(3) + loads g=w+2(3)
        // => <=6 outstanding guarantees group w+1 landed in LDS.
        if (w == 0 || w == 11) WAITV(3); else WAITV(6);

        #pragma unroll
        for (int i = 0; i < 3; ++i) {
            const int rl = rl_i[i], qf = qf_i[i];
            const int oL = offL_i[i], oR = offR_i[i];

            f4 c[3]; float l[3], r[3];
            #pragma unroll
            for (int dj = 0; dj < 3; ++dj) {
                const int ir = 4 * w + rl + dj - 1;          // band row -1..48
                const float* p = lds + ((ir >> 2) & 3) * SLOTF
                               + (ir & 3) * WW + qf;
                const f4 v     = *(const f4*)p;
                const float lv = p[oL];
                const float rv = p[oR];
                const bool ok  = (unsigned)(band0 + ir) < (unsigned)HH;
                c[dj] = ok ? v : zero;
                l[dj] = (ok && hasL_i[i]) ? lv : 0.f;
                r[dj] = (ok && hasR_i[i]) ? rv : 0.f;
            }

            f4 o;
            o.x = k00 * l[0]   + k01 * c[0].x + k02 * c[0].y
                + k10 * l[1]   + k11 * c[1].x + k12 * c[1].y
                + k20 * l[2]   + k21 * c[2].x + k22 * c[2].y;
            o.y = k00 * c[0].x + k01 * c[0].y + k02 * c[0].z
                + k10 * c[1].x + k11 * c[1].y + k12 * c[1].z
                + k20 * c[2].x + k21 * c[2].y + k22 * c[2].z;
            o.z = k00 * c[0].y + k01 * c[0].z + k02 * c[0].w
                + k10 * c[1].y + k11 * c[1].z + k12 * c[1].w
                + k20 * c[2].y + k21 * c[2].z + k22 * c[2].w;
            o.w = k00 * c[0].z + k01 * c[0].w + k02 * r[0]
                + k10 * c[1].z + k11 * c[1].w + k12 * r[1]
                + k20 * c[2].z + k21 * c[2].w + k22 * r[2];

            __builtin_nontemporal_store(
                o, (f4*)(op + (size_t)(band0 + 4 * w + rl) * WW + qf));
        }
    }
}

extern "C" void kernel_launch(void* const* d_in, const int* in_sizes, int n_in,
                              void* d_out, int out_size, void* d_ws, size_t ws_size,
                              hipStream_t stream) {
    const float* x0 = (const float*)d_in[0];  // (16,64,192,192)
    const float* d  = (const float*)d_in[1];  // (16,64)
    const float* w1 = (const float*)d_in[2];  // (64,64)
    const float* w2 = (const float*)d_in[3];  // (576,64)
    float* out = (float*)d_out;
    float* ker = (float*)d_ws;                // 9216 floats

    gen_kernels<<<BB, 256, 0, stream>>>(d, w1, w2, ker);
    dconv3x3_v8<<<BB * CC * 4, 64, 0, stream>>>(x0, ker, out);
}

// Round 6
// 271.221 us; speedup vs baseline: 1.0436x; 1.0436x over previous
//
#include <hip/hip_runtime.h>

// B=16, C=64, H=W=192, K=3 (fixed).
// Kernel 1: ker[b,c,i,j] from the tiny MLP (16 blocks, writes 9216 floats to ws).
// Kernel 2 (v9): EXACTLY the v4 structure (best measured total, 270.3 us)
// with ONE change: plain stores instead of __builtin_nontemporal_store.
//   Theory: every prior variant (v3 regs / v5 staged / v7 pipelined / v8
//   barrier-free) used NT stores and all plateaued at conv ~88-95 us,
//   ~2.4-2.6 TB/s, with every pipe idle. NT stores retire at HBM (~900 cy)
//   instead of L2 (~200 cy), so every wait/drain stalls on HBM write
//   completion; the 6.7 TB/s fill kernel uses plain stores. Single-variable
//   A/B vs round-1's v4 numbers.

#define BB 16
#define CC 64
#define HH 192
#define WW 192
#define KERLEN (CC * 9)     // 576 per batch
#define QW (WW / 4)         // 48 quads per row
#define RPT 4               // output rows per thread
#define TPP (QW * (HH / RPT))   // 48*48 = 2304 tasks per plane
#define BPP (TPP / 256)         // 9 blocks per plane

typedef float f4 __attribute__((ext_vector_type(4)));

// ---- Kernel 1: generate the 1024 per-(b,c) 3x3 kernels into d_ws ----
__global__ __launch_bounds__(256) void gen_kernels(
    const float* __restrict__ d,   // (B, C)
    const float* __restrict__ w1,  // (C, C)
    const float* __restrict__ w2,  // (C*9, C)
    float* __restrict__ ker)       // (B*C*9)
{
    __shared__ float dd[CC];
    __shared__ float hid[CC];
    const int b = blockIdx.x;
    const int t = threadIdx.x;

    if (t < CC) dd[t] = d[b * CC + t];
    __syncthreads();

    if (t < CC) {
        const float* w1r = w1 + t * CC;
        float acc = 0.f;
        #pragma unroll 8
        for (int m = 0; m < CC; ++m) acc += dd[m] * w1r[m];
        hid[t] = acc > 0.f ? acc : 0.1f * acc;
    }
    __syncthreads();

    for (int o = t; o < KERLEN; o += 256) {
        const float* w2r = w2 + o * CC;
        float acc = 0.f;
        #pragma unroll 8
        for (int k = 0; k < CC; ++k) acc += hid[k] * w2r[k];
        ker[b * KERLEN + o] = acc;
    }
}

// ---- Kernel 2: depthwise 3x3, hoisted-load 4-row strip, PLAIN stores ----
__global__ __launch_bounds__(256, 8) void dconv3x3_v9(
    const float* __restrict__ x,    // (B*C, H, W)
    const float* __restrict__ ker,  // (B*C, 9)
    float* __restrict__ out)        // (B*C, H, W)
{
    const int blk = blockIdx.x;
    const int bc  = blk / BPP;
    const int sub = blk - bc * BPP;

    // block-uniform coefficients -> scalar loads (SGPRs)
    const float* kp = ker + bc * 9;
    const float k00 = kp[0], k01 = kp[1], k02 = kp[2];
    const float k10 = kp[3], k11 = kp[4], k12 = kp[5];
    const float k20 = kp[6], k21 = kp[7], k22 = kp[8];

    const int task = sub * 256 + threadIdx.x;   // 0..2303
    const int rg   = task / QW;                 // row-group 0..47
    const int qw   = task - rg * QW;            // quad col 0..47
    const int w    = qw * 4;
    const int r0   = rg * RPT;

    const bool hasL = (qw > 0);
    const bool hasR = (qw < QW - 1);
    const int  offL = hasL ? -1 : 0;            // safe clamped offsets
    const int  offR = hasR ?  4 : 0;

    const float* __restrict__ xp = x   + (size_t)bc * HH * WW + w;
    float* __restrict__       op = out + (size_t)bc * HH * WW + w;

    f4    c[RPT + 2];
    float l[RPT + 2], r[RPT + 2];
    const f4 zero = {0.f, 0.f, 0.f, 0.f};

    // All 6 row-loads issued before any use: 6x dwordx4 + 12x dword,
    // fully independent -> deep MLP.
    #pragma unroll
    for (int j = 0; j < RPT + 2; ++j) {
        const int rr  = r0 - 1 + j;
        const int rcl = rr < 0 ? 0 : (rr >= HH ? HH - 1 : rr);
        const float* p = xp + rcl * WW;
        const f4 v     = *(const f4*)p;
        const float lv = p[offL];
        const float rv = p[offR];
        const bool ok  = (rr >= 0) & (rr < HH);
        c[j] = ok ? v : zero;
        l[j] = (ok && hasL) ? lv : 0.f;
        r[j] = (ok && hasR) ? rv : 0.f;
    }

    #pragma unroll
    for (int i = 0; i < RPT; ++i) {
        const f4 ca = c[i], cb = c[i + 1], cd = c[i + 2];
        const float la = l[i], lb = l[i + 1], lc = l[i + 2];
        const float ra = r[i], rb = r[i + 1], rc = r[i + 2];

        f4 o;
        o.x = k00 * la   + k01 * ca.x + k02 * ca.y
            + k10 * lb   + k11 * cb.x + k12 * cb.y
            + k20 * lc   + k21 * cd.x + k22 * cd.y;
        o.y = k00 * ca.x + k01 * ca.y + k02 * ca.z
            + k10 * cb.x + k11 * cb.y + k12 * cb.z
            + k20 * cd.x + k21 * cd.y + k22 * cd.z;
        o.z = k00 * ca.y + k01 * ca.z + k02 * ca.w
            + k10 * cb.y + k11 * cb.z + k12 * cb.w
            + k20 * cd.y + k21 * cd.z + k22 * cd.w;
        o.w = k00 * ca.z + k01 * ca.w + k02 * ra
            + k10 * cb.z + k11 * cb.w + k12 * rb
            + k20 * cd.z + k21 * cd.w + k22 * rc;

        // PLAIN store (the single change vs v4): retires at L2, not HBM.
        *(f4*)(op + (size_t)(r0 + i) * WW) = o;
    }
}

extern "C" void kernel_launch(void* const* d_in, const int* in_sizes, int n_in,
                              void* d_out, int out_size, void* d_ws, size_t ws_size,
                              hipStream_t stream) {
    const float* x0 = (const float*)d_in[0];  // (16,64,192,192)
    const float* d  = (const float*)d_in[1];  // (16,64)
    const float* w1 = (const float*)d_in[2];  // (64,64)
    const float* w2 = (const float*)d_in[3];  // (576,64)
    float* out = (float*)d_out;
    float* ker = (float*)d_ws;                // 9216 floats

    gen_kernels<<<BB, 256, 0, stream>>>(d, w1, w2, ker);
    dconv3x3_v9<<<BB * CC * BPP, 256, 0, stream>>>(x0, ker, out);
}